// Round 1
// baseline (8112.460 us; speedup 1.0000x reference)
//
#include <hip/hip_runtime.h>

#define N_PTS 100000
#define P     32
#define CIN   10
#define COUT  64
#define CH    32          // Cout/2
#define BN_EPS 1e-3f

constexpr int THR   = 256;               // 4 waves / block
constexpr int WPB   = 4;                 // waves per block
constexpr int BLK_A = 1024;              // pass-A blocks (partials: 1 MB ws)
constexpr int TW_A  = BLK_A * WPB;       // 4096 waves
constexpr int BLK_C = 2048;
constexpr int TW_C  = BLK_C * WPB;       // 8192 waves
constexpr int PART_FLOATS = BLK_A * 256; // partial-sum region in ws

// ---- shared per-point compute core (lane = output channel) ----
__device__ __forceinline__ void compute_point(const float* __restrict__ pp,
                                              const float* w, const float* w1,
                                              const float* w2, float* hrow,
                                              int lane, float& x, float& xa)
{
    float u[CIN];
    #pragma unroll
    for (int c = 0; c < CIN; c += 2) {          // 40B/point, 8B-aligned
        float2 t = *reinterpret_cast<const float2*>(pp + c);
        u[c] = t.x; u[c + 1] = t.y;
    }
    x = 0.f;
    #pragma unroll
    for (int c = 0; c < CIN; ++c) x = fmaf(w[c], u[c], x);

    float h = 0.f;
    #pragma unroll
    for (int c = 0; c < CIN; ++c) h = fmaf(w1[c], u[c], h);
    h = fmaxf(h, 0.f);

    // share h across the wave via wave-private LDS (same-wave DS ops are
    // in-order; wave_barrier pins compiler scheduling — no s_barrier needed)
    __builtin_amdgcn_wave_barrier();
    if (lane < CH) hrow[lane] = h;
    __builtin_amdgcn_wave_barrier();

    float g = 0.f;
    #pragma unroll
    for (int j = 0; j < CH; j += 4) {
        float4 hv = *reinterpret_cast<const float4*>(hrow + j);  // broadcast read
        g = fmaf(w2[j    ], hv.x, g);
        g = fmaf(w2[j + 1], hv.y, g);
        g = fmaf(w2[j + 2], hv.z, g);
        g = fmaf(w2[j + 3], hv.w, g);
    }
    __builtin_amdgcn_wave_barrier();

    g  = 1.f / (1.f + __expf(-g));   // sigmoid
    xa = x * g;
}

// ---- pass A: per-channel sum / sumsq for x and x_a (pre-BN) ----
__global__ void pass_a(const float* __restrict__ in, const float* __restrict__ W,
                       const float* __restrict__ W1, const float* __restrict__ W2,
                       float* __restrict__ partials)
{
    __shared__ float lds_h[WPB][CH];
    __shared__ float lds_red[WPB][4][COUT];
    const int lane = threadIdx.x & 63;
    const int wid  = threadIdx.x >> 6;
    const int gw   = blockIdx.x * WPB + wid;

    float w[CIN], w1[CIN], w2[CH];
    #pragma unroll
    for (int c = 0; c < CIN; ++c) w[c]  = W[lane * CIN + c];
    #pragma unroll
    for (int c = 0; c < CIN; ++c) w1[c] = W1[(lane & 31) * CIN + c];
    #pragma unroll
    for (int j = 0; j < CH; ++j)  w2[j] = W2[lane * CH + j];

    float s_x = 0.f, q_x = 0.f, s_a = 0.f, q_a = 0.f;

    for (int n = gw; n < N_PTS; n += TW_A) {
        const float* bp = in + (size_t)n * (P * CIN);
        #pragma unroll 4
        for (int p = 0; p < P; ++p) {
            float x, xa;
            compute_point(bp + p * CIN, w, w1, w2, lds_h[wid], lane, x, xa);
            s_x += x;  q_x = fmaf(x,  x,  q_x);
            s_a += xa; q_a = fmaf(xa, xa, q_a);
        }
    }
    lds_red[wid][0][lane] = s_x;
    lds_red[wid][1][lane] = q_x;
    lds_red[wid][2][lane] = s_a;
    lds_red[wid][3][lane] = q_a;
    __syncthreads();                       // uniform: after all loops
    const int q = threadIdx.x >> 6, c = threadIdx.x & 63;
    float s = lds_red[0][q][c] + lds_red[1][q][c] + lds_red[2][q][c] + lds_red[3][q][c];
    partials[blockIdx.x * 256 + q * 64 + c] = s;
}

// ---- pass B: reduce partials (fp64, fixed order) -> scale/bias per channel ----
__global__ void pass_b(const float* __restrict__ partials,
                       const float* __restrict__ gamma,  const float* __restrict__ beta,
                       const float* __restrict__ gamma1, const float* __restrict__ beta1,
                       float* __restrict__ params)
{
    __shared__ double lds_s[4][COUT];
    const int t = threadIdx.x;             // 256 threads = 4 quantities x 64 ch
    double acc = 0.0;
    for (int b = 0; b < BLK_A; ++b) acc += (double)partials[b * 256 + t];
    lds_s[t >> 6][t & 63] = acc;
    __syncthreads();
    if (t < COUT) {
        const double M  = (double)N_PTS * P;
        double mx = lds_s[0][t] / M;
        double vx = lds_s[1][t] / M - mx * mx;
        double ma = lds_s[2][t] / M;
        double va = lds_s[3][t] / M - ma * ma;
        float sx = (float)((double)gamma[t]  / sqrt(vx + (double)BN_EPS));
        float bx = (float)((double)beta[t]   - mx * (double)sx);
        float sa = (float)((double)gamma1[t] / sqrt(va + (double)BN_EPS));
        float ba = (float)((double)beta1[t]  - ma * (double)sa);
        params[t] = sx; params[64 + t] = bx; params[128 + t] = sa; params[192 + t] = ba;
    }
}

// ---- pass C: recompute, BN-affine + relu, mean_p / max_p, write out ----
__global__ void pass_c(const float* __restrict__ in, const float* __restrict__ W,
                       const float* __restrict__ W1, const float* __restrict__ W2,
                       const float* __restrict__ params, float* __restrict__ out)
{
    __shared__ float lds_h[WPB][CH];
    const int lane = threadIdx.x & 63;
    const int wid  = threadIdx.x >> 6;
    const int gw   = blockIdx.x * WPB + wid;

    float w[CIN], w1[CIN], w2[CH];
    #pragma unroll
    for (int c = 0; c < CIN; ++c) w[c]  = W[lane * CIN + c];
    #pragma unroll
    for (int c = 0; c < CIN; ++c) w1[c] = W1[(lane & 31) * CIN + c];
    #pragma unroll
    for (int j = 0; j < CH; ++j)  w2[j] = W2[lane * CH + j];

    const float sx = params[lane], bx = params[64 + lane];
    const float sa = params[128 + lane], ba = params[192 + lane];

    for (int n = gw; n < N_PTS; n += TW_C) {
        const float* bp = in + (size_t)n * (P * CIN);
        float acc_mean = 0.f;
        float acc_max  = 0.f;               // relu output >= 0, so 0 is identity
        #pragma unroll 4
        for (int p = 0; p < P; ++p) {
            float x, xa;
            compute_point(bp + p * CIN, w, w1, w2, lds_h[wid], lane, x, xa);
            float ya = fmaxf(fmaf(xa, sa, ba), 0.f);
            acc_mean += ya;
            float yx = fmaxf(fmaf(x, sx, bx), 0.f);
            acc_max = fmaxf(acc_max, yx);
        }
        out[(size_t)n * COUT + lane] = acc_mean * (1.f / (float)P) + acc_max;
    }
}

extern "C" void kernel_launch(void* const* d_in, const int* in_sizes, int n_in,
                              void* d_out, int out_size, void* d_ws, size_t ws_size,
                              hipStream_t stream)
{
    const float* in     = (const float*)d_in[0];
    const float* W      = (const float*)d_in[1];
    const float* W1     = (const float*)d_in[2];
    const float* W2     = (const float*)d_in[3];
    const float* gamma  = (const float*)d_in[4];
    const float* beta   = (const float*)d_in[5];
    const float* gamma1 = (const float*)d_in[6];
    const float* beta1  = (const float*)d_in[7];
    float* out      = (float*)d_out;
    float* partials = (float*)d_ws;              // PART_FLOATS floats
    float* params   = partials + PART_FLOATS;    // 256 floats

    pass_a<<<BLK_A, THR, 0, stream>>>(in, W, W1, W2, partials);
    pass_b<<<1, 256, 0, stream>>>(partials, gamma, beta, gamma1, beta1, params);
    pass_c<<<BLK_C, THR, 0, stream>>>(in, W, W1, W2, params, out);
}

// Round 2
// 894.258 us; speedup vs baseline: 9.0717x; 9.0717x over previous
//
#include <hip/hip_runtime.h>

#define N_PTS 100000
#define P     32
#define CIN   10
#define COUT  64
#define CH    32          // Cout/2
#define BN_EPS 1e-3f

constexpr int THR   = 256;               // 4 waves / block
constexpr int WPB   = 4;                 // waves per block
constexpr int BLK_A = 1024;              // pass-A blocks (partials: 1 MB ws)
constexpr int TW_A  = BLK_A * WPB;       // 4096 waves
constexpr int BLK_C = 2048;
constexpr int TW_C  = BLK_C * WPB;       // 8192 waves
constexpr int PART_FLOATS = BLK_A * 256; // partial-sum region in ws

// ---- shared per-point compute core (lane = output channel) ----
__device__ __forceinline__ void compute_point(const float* __restrict__ pp,
                                              const float* w, const float* w1,
                                              const float* w2, float* hrow,
                                              int lane, float& x, float& xa)
{
    float u[CIN];
    #pragma unroll
    for (int c = 0; c < CIN; c += 2) {          // wave-uniform addr -> s_load
        float2 t = *reinterpret_cast<const float2*>(pp + c);
        u[c] = t.x; u[c + 1] = t.y;
    }
    x = 0.f;
    #pragma unroll
    for (int c = 0; c < CIN; ++c) x = fmaf(w[c], u[c], x);

    float h = 0.f;
    #pragma unroll
    for (int c = 0; c < CIN; ++c) h = fmaf(w1[c], u[c], h);
    h = fmaxf(h, 0.f);

    // share h across the wave via wave-private LDS (same-wave DS ops are
    // in-order; wave_barrier pins compiler scheduling — no s_barrier needed)
    __builtin_amdgcn_wave_barrier();
    if (lane < CH) hrow[lane] = h;
    __builtin_amdgcn_wave_barrier();

    float g = 0.f;
    #pragma unroll
    for (int j = 0; j < CH; j += 4) {
        float4 hv = *reinterpret_cast<const float4*>(hrow + j);  // broadcast read
        g = fmaf(w2[j    ], hv.x, g);
        g = fmaf(w2[j + 1], hv.y, g);
        g = fmaf(w2[j + 2], hv.z, g);
        g = fmaf(w2[j + 3], hv.w, g);
    }
    __builtin_amdgcn_wave_barrier();

    g  = 1.f / (1.f + __expf(-g));   // sigmoid
    xa = x * g;
}

// ---- pass A: per-channel sum / sumsq for x and x_a (pre-BN) ----
// __launch_bounds__(256,4): 128-VGPR budget so w2[32]+w[10]+w1[10]+u[10]
// stay in registers. Without it the compiler picked 64 VGPR and spilled
// ~20 GB of scratch traffic to HBM (round-1 rocprof: WRITE_SIZE 12.9 GB).
__global__ __launch_bounds__(THR, 4)
void pass_a(const float* __restrict__ in, const float* __restrict__ W,
            const float* __restrict__ W1, const float* __restrict__ W2,
            float* __restrict__ partials)
{
    __shared__ float lds_h[WPB][CH];
    __shared__ float lds_red[WPB][4][COUT];
    const int lane = threadIdx.x & 63;
    const int wid  = threadIdx.x >> 6;
    const int gw   = blockIdx.x * WPB + wid;

    float w[CIN], w1[CIN], w2[CH];
    #pragma unroll
    for (int c = 0; c < CIN; ++c) w[c]  = W[lane * CIN + c];
    #pragma unroll
    for (int c = 0; c < CIN; ++c) w1[c] = W1[(lane & 31) * CIN + c];
    #pragma unroll
    for (int j = 0; j < CH; ++j)  w2[j] = W2[lane * CH + j];

    float s_x = 0.f, q_x = 0.f, s_a = 0.f, q_a = 0.f;

    for (int n = gw; n < N_PTS; n += TW_A) {
        const float* bp = in + (size_t)n * (P * CIN);
        #pragma unroll 2
        for (int p = 0; p < P; ++p) {
            float x, xa;
            compute_point(bp + p * CIN, w, w1, w2, lds_h[wid], lane, x, xa);
            s_x += x;  q_x = fmaf(x,  x,  q_x);
            s_a += xa; q_a = fmaf(xa, xa, q_a);
        }
    }
    lds_red[wid][0][lane] = s_x;
    lds_red[wid][1][lane] = q_x;
    lds_red[wid][2][lane] = s_a;
    lds_red[wid][3][lane] = q_a;
    __syncthreads();                       // uniform: after all loops
    const int q = threadIdx.x >> 6, c = threadIdx.x & 63;
    float s = lds_red[0][q][c] + lds_red[1][q][c] + lds_red[2][q][c] + lds_red[3][q][c];
    partials[blockIdx.x * 256 + q * 64 + c] = s;
}

// ---- pass B: reduce partials (fp64, fixed order) -> scale/bias per channel ----
__global__ void pass_b(const float* __restrict__ partials,
                       const float* __restrict__ gamma,  const float* __restrict__ beta,
                       const float* __restrict__ gamma1, const float* __restrict__ beta1,
                       float* __restrict__ params)
{
    __shared__ double lds_s[4][COUT];
    const int t = threadIdx.x;             // 256 threads = 4 quantities x 64 ch
    double acc = 0.0;
    for (int b = 0; b < BLK_A; ++b) acc += (double)partials[b * 256 + t];
    lds_s[t >> 6][t & 63] = acc;
    __syncthreads();
    if (t < COUT) {
        const double M  = (double)N_PTS * P;
        double mx = lds_s[0][t] / M;
        double vx = lds_s[1][t] / M - mx * mx;
        double ma = lds_s[2][t] / M;
        double va = lds_s[3][t] / M - ma * ma;
        float sx = (float)((double)gamma[t]  / sqrt(vx + (double)BN_EPS));
        float bx = (float)((double)beta[t]   - mx * (double)sx);
        float sa = (float)((double)gamma1[t] / sqrt(va + (double)BN_EPS));
        float ba = (float)((double)beta1[t]  - ma * (double)sa);
        params[t] = sx; params[64 + t] = bx; params[128 + t] = sa; params[192 + t] = ba;
    }
}

// ---- pass C: recompute, BN-affine + relu, mean_p / max_p, write out ----
__global__ __launch_bounds__(THR, 4)
void pass_c(const float* __restrict__ in, const float* __restrict__ W,
            const float* __restrict__ W1, const float* __restrict__ W2,
            const float* __restrict__ params, float* __restrict__ out)
{
    __shared__ float lds_h[WPB][CH];
    const int lane = threadIdx.x & 63;
    const int wid  = threadIdx.x >> 6;
    const int gw   = blockIdx.x * WPB + wid;

    float w[CIN], w1[CIN], w2[CH];
    #pragma unroll
    for (int c = 0; c < CIN; ++c) w[c]  = W[lane * CIN + c];
    #pragma unroll
    for (int c = 0; c < CIN; ++c) w1[c] = W1[(lane & 31) * CIN + c];
    #pragma unroll
    for (int j = 0; j < CH; ++j)  w2[j] = W2[lane * CH + j];

    const float sx = params[lane], bx = params[64 + lane];
    const float sa = params[128 + lane], ba = params[192 + lane];

    for (int n = gw; n < N_PTS; n += TW_C) {
        const float* bp = in + (size_t)n * (P * CIN);
        float acc_mean = 0.f;
        float acc_max  = 0.f;               // relu output >= 0, so 0 is identity
        #pragma unroll 2
        for (int p = 0; p < P; ++p) {
            float x, xa;
            compute_point(bp + p * CIN, w, w1, w2, lds_h[wid], lane, x, xa);
            float ya = fmaxf(fmaf(xa, sa, ba), 0.f);
            acc_mean += ya;
            float yx = fmaxf(fmaf(x, sx, bx), 0.f);
            acc_max = fmaxf(acc_max, yx);
        }
        out[(size_t)n * COUT + lane] = acc_mean * (1.f / (float)P) + acc_max;
    }
}

extern "C" void kernel_launch(void* const* d_in, const int* in_sizes, int n_in,
                              void* d_out, int out_size, void* d_ws, size_t ws_size,
                              hipStream_t stream)
{
    const float* in     = (const float*)d_in[0];
    const float* W      = (const float*)d_in[1];
    const float* W1     = (const float*)d_in[2];
    const float* W2     = (const float*)d_in[3];
    const float* gamma  = (const float*)d_in[4];
    const float* beta   = (const float*)d_in[5];
    const float* gamma1 = (const float*)d_in[6];
    const float* beta1  = (const float*)d_in[7];
    float* out      = (float*)d_out;
    float* partials = (float*)d_ws;              // PART_FLOATS floats
    float* params   = partials + PART_FLOATS;    // 256 floats

    pass_a<<<BLK_A, THR, 0, stream>>>(in, W, W1, W2, partials);
    pass_b<<<1, 256, 0, stream>>>(partials, gamma, beta, gamma1, beta1, params);
    pass_c<<<BLK_C, THR, 0, stream>>>(in, W, W1, W2, params, out);
}

// Round 3
// 230.204 us; speedup vs baseline: 35.2403x; 3.8846x over previous
//
#include <hip/hip_runtime.h>
#include <hip/hip_bf16.h>

#define NV    100000          // voxels
#define P     32
#define CIN   10
#define COUT  64
#define CH    32              // Cout/2
#define BN_EPS 1e-3f

constexpr int THR   = 256;                 // 4 waves / block
constexpr int WPB   = 4;
constexpr int BLK_A = 1024;                // partials: 1 MB in ws
constexpr int TW_A  = BLK_A * WPB;         // waves in pass A
constexpr int BLK_C = 2048;
constexpr int TW_C  = BLK_C * WPB;
constexpr int PART_FLOATS = BLK_A * 256;

typedef __attribute__((ext_vector_type(8))) short short8;   // 8 bf16 (4 VGPR)
typedef __attribute__((ext_vector_type(4))) short s16x4;    // 4 bf16 (2 VGPR)
typedef __attribute__((ext_vector_type(4))) float f32x4;

#define HLSTRIDE 40   // bf16 elems per LDS row (80 B: 16B-aligned, 2-way banks = free)

__device__ __forceinline__ short f2b(float f) {
    __hip_bfloat16 h = __float2bfloat16(f);
    short s; __builtin_memcpy(&s, &h, 2); return s;
}

// fragment from a row-major K=10 matrix row (pad k to 32): lane q=l>>4 holds k=8q..8q+7
__device__ __forceinline__ short8 load_frag10(const float* __restrict__ row, int q) {
    float f0=0.f,f1=0.f,f2=0.f,f3=0.f,f4=0.f,f5=0.f,f6=0.f,f7=0.f;
    if (q == 0) {
        float2 a = *(const float2*)(row + 0);
        float2 b = *(const float2*)(row + 2);
        float2 c = *(const float2*)(row + 4);
        float2 d = *(const float2*)(row + 6);
        f0=a.x; f1=a.y; f2=b.x; f3=b.y; f4=c.x; f5=c.y; f6=d.x; f7=d.y;
    } else if (q == 1) {
        float2 a = *(const float2*)(row + 8);
        f0=a.x; f1=a.y;
    }
    short8 r;
    r[0]=f2b(f0); r[1]=f2b(f1); r[2]=f2b(f2); r[3]=f2b(f3);
    r[4]=f2b(f4); r[5]=f2b(f5); r[6]=f2b(f6); r[7]=f2b(f7);
    return r;
}

// fragment from a row-major K=32 matrix row (full)
__device__ __forceinline__ short8 load_frag32(const float* __restrict__ row, int q) {
    const float* p = row + q * 8;
    float2 a = *(const float2*)(p + 0);
    float2 b = *(const float2*)(p + 2);
    float2 c = *(const float2*)(p + 4);
    float2 d = *(const float2*)(p + 6);
    short8 r;
    r[0]=f2b(a.x); r[1]=f2b(a.y); r[2]=f2b(b.x); r[3]=f2b(b.y);
    r[4]=f2b(c.x); r[5]=f2b(c.y); r[6]=f2b(d.x); r[7]=f2b(d.y);
    return r;
}

// One 16-point tile: X[pt,ch] (4 N-tiles) and gate-input G[pt,ch] via H bounce in LDS.
// gbase = global point index of tile start. hlw = this wave's private LDS ([16][HLSTRIDE] bf16).
__device__ __forceinline__ void tile_core(const float* __restrict__ in, long gbase,
                                          int q, int col,
                                          const short8* wB, const short8* w1A, const short8* w2B,
                                          short* hlw, f32x4 (&xacc)[4], f32x4 (&gacc)[4])
{
    const f32x4 z = {0.f, 0.f, 0.f, 0.f};
    // U fragment: A-op (row=pt=l&15, k=8q+j) == B-op (col=pt) — one load serves both
    short8 uf = load_frag10(in + (gbase + col) * CIN, q);

    f32x4 hacc[2];
    #pragma unroll
    for (int ht = 0; ht < 2; ++ht)   // H[hch, pt] = W1 (A, M=hch) x U (B, N=pt)
        hacc[ht] = __builtin_amdgcn_mfma_f32_16x16x32_bf16(w1A[ht], uf, z, 0, 0, 0);
    #pragma unroll
    for (int c = 0; c < 4; ++c)      // X[pt, ch] = U (A, M=pt) x W^T (B, N=ch)
        xacc[c] = __builtin_amdgcn_mfma_f32_16x16x32_bf16(uf, wB[c], z, 0, 0, 0);

    // relu(H) -> bf16 -> LDS laid out [pt][hch] so it reloads as G's A-operand
    __builtin_amdgcn_wave_barrier();
    #pragma unroll
    for (int ht = 0; ht < 2; ++ht) {   // lane holds rows hch=ht*16+4q+r of col pt=col
        s16x4 v;
        #pragma unroll
        for (int r = 0; r < 4; ++r) v[r] = f2b(fmaxf(hacc[ht][r], 0.f));
        *reinterpret_cast<s16x4*>(hlw + col * HLSTRIDE + ht * 16 + 4 * q) = v;
    }
    __builtin_amdgcn_wave_barrier();
    short8 af = *reinterpret_cast<const short8*>(hlw + col * HLSTRIDE + 8 * q);
    __builtin_amdgcn_wave_barrier();

    #pragma unroll
    for (int c = 0; c < 4; ++c)      // G[pt, ch] = H^T (A, M=pt, k=hch) x W2^T (B, N=ch)
        gacc[c] = __builtin_amdgcn_mfma_f32_16x16x32_bf16(af, w2B[c], z, 0, 0, 0);
}

// ---- pass A: BN batch stats (sum / sumsq of x and x_a) ----
__global__ __launch_bounds__(THR, 2)
void pass_a(const float* __restrict__ in, const float* __restrict__ W,
            const float* __restrict__ W1, const float* __restrict__ W2,
            float* __restrict__ partials)
{
    __shared__ short hl[WPB][16 * HLSTRIDE];
    __shared__ float red[WPB][4][4][16];       // [wid][quant][cht][col]
    const int lane = threadIdx.x & 63, wid = threadIdx.x >> 6;
    const int q = lane >> 4, col = lane & 15;
    const int gw = blockIdx.x * WPB + wid;
    short* hlw = &hl[wid][0];

    short8 wB[4], w1A[2], w2B[4];
    #pragma unroll
    for (int c = 0; c < 4; ++c)  wB[c]  = load_frag10(W  + (c * 16 + col) * CIN, q);
    #pragma unroll
    for (int t = 0; t < 2; ++t)  w1A[t] = load_frag10(W1 + (t * 16 + col) * CIN, q);
    #pragma unroll
    for (int c = 0; c < 4; ++c)  w2B[c] = load_frag32(W2 + (c * 16 + col) * CH, q);

    float sx[4] = {0,0,0,0}, qx[4] = {0,0,0,0}, sa[4] = {0,0,0,0}, qa[4] = {0,0,0,0};

    for (int n = gw; n < NV; n += TW_A) {
        #pragma unroll
        for (int ptt = 0; ptt < 2; ++ptt) {
            f32x4 xacc[4], gacc[4];
            tile_core(in, (long)n * P + ptt * 16, q, col, wB, w1A, w2B, hlw, xacc, gacc);
            #pragma unroll
            for (int c = 0; c < 4; ++c)
                #pragma unroll
                for (int r = 0; r < 4; ++r) {
                    float x = xacc[c][r], g = gacc[c][r];
                    float sg = __builtin_amdgcn_rcpf(1.f + __expf(-g));
                    float xa = x * sg;
                    sx[c] += x;  qx[c] = fmaf(x,  x,  qx[c]);
                    sa[c] += xa; qa[c] = fmaf(xa, xa, qa[c]);
                }
        }
    }
    // reduce across q groups (points live on rows): lanes differing in bits 4,5 share (col,cht)
    #pragma unroll
    for (int c = 0; c < 4; ++c) {
        sx[c] += __shfl_xor(sx[c], 16); sx[c] += __shfl_xor(sx[c], 32);
        qx[c] += __shfl_xor(qx[c], 16); qx[c] += __shfl_xor(qx[c], 32);
        sa[c] += __shfl_xor(sa[c], 16); sa[c] += __shfl_xor(sa[c], 32);
        qa[c] += __shfl_xor(qa[c], 16); qa[c] += __shfl_xor(qa[c], 32);
    }
    #pragma unroll
    for (int c = 0; c < 4; ++c) {     // quantity selected by q (all q-copies identical)
        float v = (q == 0) ? sx[c] : (q == 1) ? qx[c] : (q == 2) ? sa[c] : qa[c];
        red[wid][q][c][col] = v;
    }
    __syncthreads();
    const int t = threadIdx.x, quant = t >> 6, ch = t & 63;
    float s = red[0][quant][ch >> 4][ch & 15] + red[1][quant][ch >> 4][ch & 15]
            + red[2][quant][ch >> 4][ch & 15] + red[3][quant][ch >> 4][ch & 15];
    partials[blockIdx.x * 256 + t] = s;
}

// ---- pass B: fp64 fixed-order reduce -> per-channel scale/bias ----
__global__ void pass_b(const float* __restrict__ partials,
                       const float* __restrict__ gamma,  const float* __restrict__ beta,
                       const float* __restrict__ gamma1, const float* __restrict__ beta1,
                       float* __restrict__ params)
{
    __shared__ double lds_s[4][COUT];
    const int t = threadIdx.x;
    double acc = 0.0;
    for (int b = 0; b < BLK_A; ++b) acc += (double)partials[b * 256 + t];
    lds_s[t >> 6][t & 63] = acc;
    __syncthreads();
    if (t < COUT) {
        const double M = (double)NV * P;
        double mx = lds_s[0][t] / M;
        double vx = lds_s[1][t] / M - mx * mx;
        double ma = lds_s[2][t] / M;
        double va = lds_s[3][t] / M - ma * ma;
        float sxp = (float)((double)gamma[t]  / sqrt(vx + (double)BN_EPS));
        float bxp = (float)((double)beta[t]   - mx * (double)sxp);
        float sap = (float)((double)gamma1[t] / sqrt(va + (double)BN_EPS));
        float bap = (float)((double)beta1[t]  - ma * (double)sap);
        params[t] = sxp; params[64 + t] = bxp; params[128 + t] = sap; params[192 + t] = bap;
    }
}

// ---- pass C: recompute, BN-affine+relu, mean_p / max_p, coalesced out ----
__global__ __launch_bounds__(THR, 2)
void pass_c(const float* __restrict__ in, const float* __restrict__ W,
            const float* __restrict__ W1, const float* __restrict__ W2,
            const float* __restrict__ params, float* __restrict__ out)
{
    __shared__ short hl[WPB][16 * HLSTRIDE];
    const int lane = threadIdx.x & 63, wid = threadIdx.x >> 6;
    const int q = lane >> 4, col = lane & 15;
    const int gw = blockIdx.x * WPB + wid;
    short* hlw = &hl[wid][0];

    short8 wB[4], w1A[2], w2B[4];
    #pragma unroll
    for (int c = 0; c < 4; ++c)  wB[c]  = load_frag10(W  + (c * 16 + col) * CIN, q);
    #pragma unroll
    for (int t = 0; t < 2; ++t)  w1A[t] = load_frag10(W1 + (t * 16 + col) * CIN, q);
    #pragma unroll
    for (int c = 0; c < 4; ++c)  w2B[c] = load_frag32(W2 + (c * 16 + col) * CH, q);

    float sxp[4], bxp[4], sap[4], bap[4];
    #pragma unroll
    for (int c = 0; c < 4; ++c) {
        int ch = c * 16 + col;
        sxp[c] = params[ch]; bxp[c] = params[64 + ch];
        sap[c] = params[128 + ch]; bap[c] = params[192 + ch];
    }

    for (int n = gw; n < NV; n += TW_C) {
        float macc[4] = {0,0,0,0}, xmax[4] = {0,0,0,0};   // relu out >= 0 -> 0 is max-identity
        #pragma unroll
        for (int ptt = 0; ptt < 2; ++ptt) {
            f32x4 xacc[4], gacc[4];
            tile_core(in, (long)n * P + ptt * 16, q, col, wB, w1A, w2B, hlw, xacc, gacc);
            #pragma unroll
            for (int c = 0; c < 4; ++c)
                #pragma unroll
                for (int r = 0; r < 4; ++r) {
                    float x = xacc[c][r], g = gacc[c][r];
                    float sg = __builtin_amdgcn_rcpf(1.f + __expf(-g));
                    float xa = x * sg;
                    float ya = fmaxf(fmaf(xa, sap[c], bap[c]), 0.f);
                    macc[c] += ya;
                    float yx = fmaxf(fmaf(x, sxp[c], bxp[c]), 0.f);
                    xmax[c] = fmaxf(xmax[c], yx);
                }
        }
        #pragma unroll
        for (int c = 0; c < 4; ++c) {   // reduce over points (q groups)
            macc[c] += __shfl_xor(macc[c], 16); macc[c] += __shfl_xor(macc[c], 32);
            xmax[c] = fmaxf(xmax[c], __shfl_xor(xmax[c], 16));
            xmax[c] = fmaxf(xmax[c], __shfl_xor(xmax[c], 32));
        }
        float m  = (q == 0) ? macc[0] : (q == 1) ? macc[1] : (q == 2) ? macc[2] : macc[3];
        float xm = (q == 0) ? xmax[0] : (q == 1) ? xmax[1] : (q == 2) ? xmax[2] : xmax[3];
        out[(size_t)n * COUT + q * 16 + col] = m * (1.f / (float)P) + xm;   // lane==ch: coalesced
    }
}

extern "C" void kernel_launch(void* const* d_in, const int* in_sizes, int n_in,
                              void* d_out, int out_size, void* d_ws, size_t ws_size,
                              hipStream_t stream)
{
    const float* in     = (const float*)d_in[0];
    const float* W      = (const float*)d_in[1];
    const float* W1     = (const float*)d_in[2];
    const float* W2     = (const float*)d_in[3];
    const float* gamma  = (const float*)d_in[4];
    const float* beta   = (const float*)d_in[5];
    const float* gamma1 = (const float*)d_in[6];
    const float* beta1  = (const float*)d_in[7];
    float* outp     = (float*)d_out;
    float* partials = (float*)d_ws;
    float* params   = partials + PART_FLOATS;

    pass_a<<<BLK_A, THR, 0, stream>>>(in, W, W1, W2, partials);
    pass_b<<<1, 256, 0, stream>>>(partials, gamma, beta, gamma1, beta1, params);
    pass_c<<<BLK_C, THR, 0, stream>>>(in, W, W1, W2, params, outp);
}

// Round 4
// 196.524 us; speedup vs baseline: 41.2797x; 1.1714x over previous
//
#include <hip/hip_runtime.h>
#include <hip/hip_bf16.h>

#define NV    100000          // voxels
#define P     32
#define CIN   10
#define COUT  64
#define CH    32              // Cout/2
#define BN_EPS 1e-3f

constexpr int THR   = 256;                 // 4 waves / block
constexpr int WPB   = 4;
constexpr int BLK_A = 1024;                // partials: 1 MB in ws
constexpr int TW_A  = BLK_A * WPB;
constexpr int BLK_C = 2048;
constexpr int TW_C  = BLK_C * WPB;
constexpr int PART_FLOATS = BLK_A * 256;

typedef __attribute__((ext_vector_type(8)))  short short8;   // 8 bf16
typedef __attribute__((ext_vector_type(4)))  short s16x4;    // 4 bf16
typedef __attribute__((ext_vector_type(16))) float f32x16;   // 32x32 C/D
typedef __attribute__((ext_vector_type(2)))  float f32x2;

#define HLS 36   // shorts per LDS point-row (72 B) -> all DS ops are 8 B, ~2-way banks (free)

__device__ __forceinline__ short f2b(float f) {
    __hip_bfloat16 h = __float2bfloat16(f);
    short s; __builtin_memcpy(&s, &h, 2); return s;
}

// K=10 row padded to K=16: lane-half hi holds k = 8*hi + j (j=0..7)
__device__ __forceinline__ short8 load_k10(const float* __restrict__ row, int hi) {
    float f0=0.f,f1=0.f,f2=0.f,f3=0.f,f4=0.f,f5=0.f,f6=0.f,f7=0.f;
    if (hi == 0) {
        float2 a = *(const float2*)(row);     float2 b = *(const float2*)(row + 2);
        float2 c = *(const float2*)(row + 4); float2 d = *(const float2*)(row + 6);
        f0=a.x; f1=a.y; f2=b.x; f3=b.y; f4=c.x; f5=c.y; f6=d.x; f7=d.y;
    } else {
        float2 a = *(const float2*)(row + 8);
        f0=a.x; f1=a.y;
    }
    short8 r;
    r[0]=f2b(f0); r[1]=f2b(f1); r[2]=f2b(f2); r[3]=f2b(f3);
    r[4]=f2b(f4); r[5]=f2b(f5); r[6]=f2b(f6); r[7]=f2b(f7);
    return r;
}

__device__ __forceinline__ short8 load_k8(const float* __restrict__ p) {  // 8 consecutive floats
    float2 a = *(const float2*)(p);     float2 b = *(const float2*)(p + 2);
    float2 c = *(const float2*)(p + 4); float2 d = *(const float2*)(p + 6);
    short8 r;
    r[0]=f2b(a.x); r[1]=f2b(a.y); r[2]=f2b(b.x); r[3]=f2b(b.y);
    r[4]=f2b(c.x); r[5]=f2b(c.y); r[6]=f2b(d.x); r[7]=f2b(d.y);
    return r;
}

__device__ __forceinline__ f32x2 sigm2(f32x2 g) {   // 1/(1+exp(-g)), componentwise
    f32x2 s;
    float ex = __expf(-g.x), ey = __expf(-g.y);
    s.x = __builtin_amdgcn_rcpf(1.f + ex);
    s.y = __builtin_amdgcn_rcpf(1.f + ey);
    return s;
}

// One voxel (32 points): X[pt,ch] in x0/x1 (ch tiles), gate-logit G[pt,ch] in g0/g1.
// 32x32x16 layouts: A row = l&31, k = 8*(l>>5)+j ; B col = l&31, same k ;
// C/D col = l&31, row = (reg&3) + 8*(reg>>2) + 4*(l>>5).
__device__ __forceinline__ void voxel_core(const float* __restrict__ in, int n,
        int hi, int col, const short8* wB, const short8 w1A,
        const short8 (&w2B)[2][2], short* __restrict__ hlw,
        f32x16& x0, f32x16& x1, f32x16& g0, f32x16& g1)
{
    const f32x16 z = {0.f,0.f,0.f,0.f,0.f,0.f,0.f,0.f,0.f,0.f,0.f,0.f,0.f,0.f,0.f,0.f};
    const float* up = in + ((long)n * P + col) * CIN;   // col = point index
    short8 uf = load_k10(up, hi);                        // serves as A (M=pt) and B (N=pt)

    f32x16 hacc = __builtin_amdgcn_mfma_f32_32x32x16_bf16(w1A, uf, z, 0, 0, 0); // H[hch,pt]
    x0 = __builtin_amdgcn_mfma_f32_32x32x16_bf16(uf, wB[0], z, 0, 0, 0);        // X[pt,ch0-31]
    x1 = __builtin_amdgcn_mfma_f32_32x32x16_bf16(uf, wB[1], z, 0, 0, 0);        // X[pt,ch32-63]

    // relu(H) -> bf16 -> LDS [pt][hch] (row layout linear in hch)
    __builtin_amdgcn_wave_barrier();
    #pragma unroll
    for (int gq = 0; gq < 4; ++gq) {          // lane's rows: hch = 8*gq + 4*hi + (0..3)
        s16x4 v;
        #pragma unroll
        for (int r = 0; r < 4; ++r) v[r] = f2b(fmaxf(hacc[4 * gq + r], 0.f));
        *reinterpret_cast<s16x4*>(hlw + col * HLS + 8 * gq + 4 * hi) = v;
    }
    __builtin_amdgcn_wave_barrier();
    short8 af0, af1;                          // G's A-frags: row=pt=col, k=hch=16*kt+8*hi+j
    {
        s16x4 a = *(const s16x4*)(hlw + col * HLS + 8 * hi);
        s16x4 b = *(const s16x4*)(hlw + col * HLS + 8 * hi + 4);
        s16x4 c = *(const s16x4*)(hlw + col * HLS + 16 + 8 * hi);
        s16x4 d = *(const s16x4*)(hlw + col * HLS + 16 + 8 * hi + 4);
        #pragma unroll
        for (int j = 0; j < 4; ++j) { af0[j] = a[j]; af0[4 + j] = b[j];
                                      af1[j] = c[j]; af1[4 + j] = d[j]; }
    }
    __builtin_amdgcn_wave_barrier();
    g0 = __builtin_amdgcn_mfma_f32_32x32x16_bf16(af0, w2B[0][0], z,  0, 0, 0);
    g0 = __builtin_amdgcn_mfma_f32_32x32x16_bf16(af1, w2B[0][1], g0, 0, 0, 0);
    g1 = __builtin_amdgcn_mfma_f32_32x32x16_bf16(af0, w2B[1][0], z,  0, 0, 0);
    g1 = __builtin_amdgcn_mfma_f32_32x32x16_bf16(af1, w2B[1][1], g1, 0, 0, 0);
}

// ---- pass A: BN batch stats ----
__global__ __launch_bounds__(THR, 2)
void pass_a(const float* __restrict__ in, const float* __restrict__ W,
            const float* __restrict__ W1, const float* __restrict__ W2,
            float* __restrict__ partials)
{
    __shared__ short hl[WPB][32 * HLS];
    __shared__ float red[WPB][4][32][2];     // [wid][quant][col][tile]
    const int lane = threadIdx.x & 63, wid = threadIdx.x >> 6;
    const int hi = lane >> 5, col = lane & 31;
    const int gw = blockIdx.x * WPB + wid;
    short* hlw = &hl[wid][0];

    short8 wB[2];
    wB[0] = load_k10(W + col * CIN, hi);
    wB[1] = load_k10(W + (32 + col) * CIN, hi);
    short8 w1A = load_k10(W1 + col * CIN, hi);
    short8 w2B[2][2];
    #pragma unroll
    for (int nt = 0; nt < 2; ++nt)
        #pragma unroll
        for (int kt = 0; kt < 2; ++kt)
            w2B[nt][kt] = load_k8(W2 + (nt * 32 + col) * CH + kt * 16 + hi * 8);

    f32x2 sx[2], qx[2], sa[2], qa[2];
    #pragma unroll
    for (int nt = 0; nt < 2; ++nt) { sx[nt]=(f32x2){0,0}; qx[nt]=(f32x2){0,0};
                                     sa[nt]=(f32x2){0,0}; qa[nt]=(f32x2){0,0}; }

    for (int n = gw; n < NV; n += TW_A) {
        f32x16 x0, x1, g0, g1;
        voxel_core(in, n, hi, col, wB, w1A, w2B, hlw, x0, x1, g0, g1);
        #pragma unroll
        for (int nt = 0; nt < 2; ++nt) {
            const f32x16& X = nt ? x1 : x0;
            const f32x16& G = nt ? g1 : g0;
            #pragma unroll
            for (int r = 0; r < 8; ++r) {
                f32x2 x2 = {X[2*r], X[2*r+1]};
                f32x2 g2 = {G[2*r], G[2*r+1]};
                f32x2 s2 = sigm2(g2);
                f32x2 xa2 = x2 * s2;
                sx[nt] += x2;  qx[nt] = __builtin_elementwise_fma(x2, x2, qx[nt]);
                sa[nt] += xa2; qa[nt] = __builtin_elementwise_fma(xa2, xa2, qa[nt]);
            }
        }
    }
    #pragma unroll
    for (int nt = 0; nt < 2; ++nt) {
        float vsx = sx[nt].x + sx[nt].y;  vsx += __shfl_xor(vsx, 32);
        float vqx = qx[nt].x + qx[nt].y;  vqx += __shfl_xor(vqx, 32);
        float vsa = sa[nt].x + sa[nt].y;  vsa += __shfl_xor(vsa, 32);
        float vqa = qa[nt].x + qa[nt].y;  vqa += __shfl_xor(vqa, 32);
        if (hi == 0) {
            red[wid][0][col][nt] = vsx; red[wid][1][col][nt] = vqx;
            red[wid][2][col][nt] = vsa; red[wid][3][col][nt] = vqa;
        }
    }
    __syncthreads();
    const int t = threadIdx.x, q = t >> 6, ch = t & 63, nt = ch >> 5, c = ch & 31;
    float s = red[0][q][c][nt] + red[1][q][c][nt] + red[2][q][c][nt] + red[3][q][c][nt];
    partials[blockIdx.x * 256 + t] = s;
}

// ---- pass B: fp64 fixed-order reduce -> per-channel scale/bias ----
__global__ void pass_b(const float* __restrict__ partials,
                       const float* __restrict__ gamma,  const float* __restrict__ beta,
                       const float* __restrict__ gamma1, const float* __restrict__ beta1,
                       float* __restrict__ params)
{
    __shared__ double lds_s[4][COUT];
    const int t = threadIdx.x;
    double acc = 0.0;
    for (int b = 0; b < BLK_A; ++b) acc += (double)partials[b * 256 + t];
    lds_s[t >> 6][t & 63] = acc;
    __syncthreads();
    if (t < COUT) {
        const double M = (double)NV * P;
        double mx = lds_s[0][t] / M;
        double vx = lds_s[1][t] / M - mx * mx;
        double ma = lds_s[2][t] / M;
        double va = lds_s[3][t] / M - ma * ma;
        float sxp = (float)((double)gamma[t]  / sqrt(vx + (double)BN_EPS));
        float bxp = (float)((double)beta[t]   - mx * (double)sxp);
        float sap = (float)((double)gamma1[t] / sqrt(va + (double)BN_EPS));
        float bap = (float)((double)beta1[t]  - ma * (double)sap);
        params[t] = sxp; params[64 + t] = bxp; params[128 + t] = sap; params[192 + t] = bap;
    }
}

// ---- pass C: recompute, BN-affine+relu, mean_p / max_p, coalesced out ----
__global__ __launch_bounds__(THR, 2)
void pass_c(const float* __restrict__ in, const float* __restrict__ W,
            const float* __restrict__ W1, const float* __restrict__ W2,
            const float* __restrict__ params, float* __restrict__ out)
{
    __shared__ short hl[WPB][32 * HLS];
    const int lane = threadIdx.x & 63, wid = threadIdx.x >> 6;
    const int hi = lane >> 5, col = lane & 31;
    const int gw = blockIdx.x * WPB + wid;
    short* hlw = &hl[wid][0];

    short8 wB[2];
    wB[0] = load_k10(W + col * CIN, hi);
    wB[1] = load_k10(W + (32 + col) * CIN, hi);
    short8 w1A = load_k10(W1 + col * CIN, hi);
    short8 w2B[2][2];
    #pragma unroll
    for (int nt = 0; nt < 2; ++nt)
        #pragma unroll
        for (int kt = 0; kt < 2; ++kt)
            w2B[nt][kt] = load_k8(W2 + (nt * 32 + col) * CH + kt * 16 + hi * 8);

    f32x2 sxv[2], bxv[2], sav[2], bav[2];     // per-lane channel params, splat to pairs
    #pragma unroll
    for (int nt = 0; nt < 2; ++nt) {
        int ch = nt * 32 + col;
        sxv[nt] = (f32x2){params[ch],       params[ch]};
        bxv[nt] = (f32x2){params[64 + ch],  params[64 + ch]};
        sav[nt] = (f32x2){params[128 + ch], params[128 + ch]};
        bav[nt] = (f32x2){params[192 + ch], params[192 + ch]};
    }

    for (int n = gw; n < NV; n += TW_C) {
        f32x16 x0, x1, g0, g1;
        voxel_core(in, n, hi, col, wB, w1A, w2B, hlw, x0, x1, g0, g1);
        f32x2 macc[2], xmax[2];
        #pragma unroll
        for (int nt = 0; nt < 2; ++nt) { macc[nt]=(f32x2){0,0}; xmax[nt]=(f32x2){0,0}; }
        #pragma unroll
        for (int nt = 0; nt < 2; ++nt) {
            const f32x16& X = nt ? x1 : x0;
            const f32x16& G = nt ? g1 : g0;
            #pragma unroll
            for (int r = 0; r < 8; ++r) {
                f32x2 x2 = {X[2*r], X[2*r+1]};
                f32x2 g2 = {G[2*r], G[2*r+1]};
                f32x2 s2 = sigm2(g2);
                f32x2 xa2 = x2 * s2;
                f32x2 zero = {0.f, 0.f};
                f32x2 ya2 = __builtin_elementwise_max(
                                __builtin_elementwise_fma(xa2, sav[nt], bav[nt]), zero);
                macc[nt] += ya2;
                f32x2 yx2 = __builtin_elementwise_max(
                                __builtin_elementwise_fma(x2, sxv[nt], bxv[nt]), zero);
                xmax[nt] = __builtin_elementwise_max(xmax[nt], yx2);   // relu>=0: 0 is identity
            }
        }
        float m0 = macc[0].x + macc[0].y;  m0 += __shfl_xor(m0, 32);
        float m1 = macc[1].x + macc[1].y;  m1 += __shfl_xor(m1, 32);
        float v0 = fmaxf(xmax[0].x, xmax[0].y); v0 = fmaxf(v0, __shfl_xor(v0, 32));
        float v1 = fmaxf(xmax[1].x, xmax[1].y); v1 = fmaxf(v1, __shfl_xor(v1, 32));
        float m  = hi ? m1 : m0;
        float v  = hi ? v1 : v0;
        out[(size_t)n * COUT + lane] = m * (1.f / (float)P) + v;   // lane == channel
    }
}

extern "C" void kernel_launch(void* const* d_in, const int* in_sizes, int n_in,
                              void* d_out, int out_size, void* d_ws, size_t ws_size,
                              hipStream_t stream)
{
    const float* in     = (const float*)d_in[0];
    const float* W      = (const float*)d_in[1];
    const float* W1     = (const float*)d_in[2];
    const float* W2     = (const float*)d_in[3];
    const float* gamma  = (const float*)d_in[4];
    const float* beta   = (const float*)d_in[5];
    const float* gamma1 = (const float*)d_in[6];
    const float* beta1  = (const float*)d_in[7];
    float* outp     = (float*)d_out;
    float* partials = (float*)d_ws;
    float* params   = partials + PART_FLOATS;

    pass_a<<<BLK_A, THR, 0, stream>>>(in, W, W1, W2, partials);
    pass_b<<<1, 256, 0, stream>>>(partials, gamma, beta, gamma1, beta1, params);
    pass_c<<<BLK_C, THR, 0, stream>>>(in, W, W1, W2, params, outp);
}

// Round 5
// 181.901 us; speedup vs baseline: 44.5982x; 1.0804x over previous
//
#include <hip/hip_runtime.h>
#include <hip/hip_bf16.h>

#define NV    100000          // voxels
#define P     32
#define CIN   10
#define COUT  64
#define CH    32              // Cout/2
#define BN_EPS 1e-3f

constexpr int THR_A = 512;                 // 8 waves / block
constexpr int WPB_A = 8;
constexpr int BLK_A = 512;                 // 4096 waves = exactly resident at 4/SIMD
constexpr int TW_A  = BLK_A * WPB_A;
constexpr int THR_C = 256;
constexpr int WPB_C = 4;
constexpr int BLK_C = 2048;
constexpr int TW_C  = BLK_C * WPB_C;
constexpr int PART_FLOATS = BLK_A * 256;   // 512 KB

typedef __attribute__((ext_vector_type(8)))  short short8;   // 8 bf16
typedef __attribute__((ext_vector_type(4)))  short s16x4;    // 4 bf16
typedef __attribute__((ext_vector_type(16))) float f32x16;   // 32x32 C/D
typedef __attribute__((ext_vector_type(2)))  float f32x2;

#define HLS 40   // shorts per LDS point-row (80 B, 16B-aligned for b128 reads)

__device__ __forceinline__ short f2b(float f) {
    __hip_bfloat16 h = __float2bfloat16(f);
    short s; __builtin_memcpy(&s, &h, 2); return s;
}

// K=10 row padded to K=16: lane-half hi holds k = 8*hi + j (j=0..7)
__device__ __forceinline__ short8 load_k10(const float* __restrict__ row, int hi) {
    float f0=0.f,f1=0.f,f2=0.f,f3=0.f,f4=0.f,f5=0.f,f6=0.f,f7=0.f;
    if (hi == 0) {
        float2 a = *(const float2*)(row);     float2 b = *(const float2*)(row + 2);
        float2 c = *(const float2*)(row + 4); float2 d = *(const float2*)(row + 6);
        f0=a.x; f1=a.y; f2=b.x; f3=b.y; f4=c.x; f5=c.y; f6=d.x; f7=d.y;
    } else {
        float2 a = *(const float2*)(row + 8);
        f0=a.x; f1=a.y;
    }
    short8 r;
    r[0]=f2b(f0); r[1]=f2b(f1); r[2]=f2b(f2); r[3]=f2b(f3);
    r[4]=f2b(f4); r[5]=f2b(f5); r[6]=f2b(f6); r[7]=f2b(f7);
    return r;
}

__device__ __forceinline__ short8 load_k8(const float* __restrict__ p) {
    float2 a = *(const float2*)(p);     float2 b = *(const float2*)(p + 2);
    float2 c = *(const float2*)(p + 4); float2 d = *(const float2*)(p + 6);
    short8 r;
    r[0]=f2b(a.x); r[1]=f2b(a.y); r[2]=f2b(b.x); r[3]=f2b(b.y);
    r[4]=f2b(c.x); r[5]=f2b(c.y); r[6]=f2b(d.x); r[7]=f2b(d.y);
    return r;
}

// sigmoid pair with ONE rcp: sig(a)=1/A, sig(b)=1/B; r=rcp(A*B) -> (r*B, r*A)
__device__ __forceinline__ f32x2 sigm2(f32x2 g) {
    float A = 1.f + __expf(-g.x);
    float B = 1.f + __expf(-g.y);
    float r = __builtin_amdgcn_rcpf(A * B);
    return (f32x2){r * B, r * A};
}

// One voxel (32 points). 32x32x16 layouts: A row=l&31, k=8*(l>>5)+j ; B col=l&31 ;
// C/D col=l&31, row=(reg&3)+8*(reg>>2)+4*(l>>5).
// wro.*: swizzled LDS short-offsets for the 4 H-writeback chunks (gq=0..3);
// rdo0/rdo1: swizzled b128 read offsets (hch 8hi..8hi+7 / 16+8hi..16+8hi+7).
__device__ __forceinline__ void voxel_core(const float* __restrict__ up, int hi,
        const short8* wB, const short8 w1A, const short8 (&w2B)[2][2],
        short* __restrict__ hlw, int4 wro, int rdo0, int rdo1,
        f32x16& x0, f32x16& x1, f32x16& g0, f32x16& g1)
{
    const f32x16 z = {0.f,0.f,0.f,0.f,0.f,0.f,0.f,0.f,0.f,0.f,0.f,0.f,0.f,0.f,0.f,0.f};
    const f32x2 zero2 = {0.f, 0.f};
    short8 uf = load_k10(up, hi);                       // A (M=pt) and B (N=pt)

    f32x16 hacc = __builtin_amdgcn_mfma_f32_32x32x16_bf16(w1A, uf, z, 0, 0, 0); // H[hch,pt]

    // relu(H) -> bf16 -> LDS (pk-max pairs; offsets precomputed+swizzled)
    __builtin_amdgcn_wave_barrier();
    #pragma unroll
    for (int gq = 0; gq < 4; ++gq) {
        f32x2 a = {hacc[4*gq],     hacc[4*gq + 1]};
        f32x2 b = {hacc[4*gq + 2], hacc[4*gq + 3]};
        a = __builtin_elementwise_max(a, zero2);
        b = __builtin_elementwise_max(b, zero2);
        s16x4 v; v[0]=f2b(a.x); v[1]=f2b(a.y); v[2]=f2b(b.x); v[3]=f2b(b.y);
        int off = (gq==0) ? wro.x : (gq==1) ? wro.y : (gq==2) ? wro.z : wro.w;
        *reinterpret_cast<s16x4*>(hlw + off) = v;
    }
    __builtin_amdgcn_wave_barrier();
    short8 af0 = *reinterpret_cast<const short8*>(hlw + rdo0);
    short8 af1 = *reinterpret_cast<const short8*>(hlw + rdo1);
    __builtin_amdgcn_wave_barrier();

    // x MFMAs here: independent work that hides the ds_read latency
    x0 = __builtin_amdgcn_mfma_f32_32x32x16_bf16(uf, wB[0], z, 0, 0, 0);
    x1 = __builtin_amdgcn_mfma_f32_32x32x16_bf16(uf, wB[1], z, 0, 0, 0);

    g0 = __builtin_amdgcn_mfma_f32_32x32x16_bf16(af0, w2B[0][0], z,  0, 0, 0);
    g0 = __builtin_amdgcn_mfma_f32_32x32x16_bf16(af1, w2B[0][1], g0, 0, 0, 0);
    g1 = __builtin_amdgcn_mfma_f32_32x32x16_bf16(af0, w2B[1][0], z,  0, 0, 0);
    g1 = __builtin_amdgcn_mfma_f32_32x32x16_bf16(af1, w2B[1][1], g1, 0, 0, 0);
}

// LDS offsets: 80 B/row, XOR-swizzle 16B-block index with sw=(col>>3)&3 so the
// 32-lane column walk stays <=2-way on banks (free).  write chunk gq at half hi:
// short-off = col*40 + 8*(gq^sw) + 4*hi ; read block b: col*40 + 8*(b^sw).
__device__ __forceinline__ void lds_offsets(int col, int hi, int4& wro, int& rdo0, int& rdo1) {
    const int sw = (col >> 3) & 3;
    wro.x = col*HLS + 8*(0^sw) + 4*hi;
    wro.y = col*HLS + 8*(1^sw) + 4*hi;
    wro.z = col*HLS + 8*(2^sw) + 4*hi;
    wro.w = col*HLS + 8*(3^sw) + 4*hi;
    rdo0  = col*HLS + 8*(hi ^ sw);
    rdo1  = col*HLS + 8*((2 + hi) ^ sw);
}

// ---- pass A: BN batch stats ----
__global__ __launch_bounds__(THR_A, 4)
void pass_a(const float* __restrict__ in, const float* __restrict__ W,
            const float* __restrict__ W1, const float* __restrict__ W2,
            float* __restrict__ partials)
{
    __shared__ short hl[WPB_A][32 * HLS];
    __shared__ float red[WPB_A][4][32][2];     // [wid][quant][col][tile]
    const int lane = threadIdx.x & 63, wid = threadIdx.x >> 6;
    const int hi = lane >> 5, col = lane & 31;
    const int gw = blockIdx.x * WPB_A + wid;
    short* hlw = &hl[wid][0];
    int4 wro; int rdo0, rdo1;
    lds_offsets(col, hi, wro, rdo0, rdo1);

    short8 wB[2];
    wB[0] = load_k10(W + col * CIN, hi);
    wB[1] = load_k10(W + (32 + col) * CIN, hi);
    short8 w1A = load_k10(W1 + col * CIN, hi);
    short8 w2B[2][2];
    #pragma unroll
    for (int nt = 0; nt < 2; ++nt)
        #pragma unroll
        for (int kt = 0; kt < 2; ++kt)
            w2B[nt][kt] = load_k8(W2 + (nt * 32 + col) * CH + kt * 16 + hi * 8);

    f32x2 sx[2], qx[2], sa[2], qa[2];
    #pragma unroll
    for (int nt = 0; nt < 2; ++nt) { sx[nt]=(f32x2){0,0}; qx[nt]=(f32x2){0,0};
                                     sa[nt]=(f32x2){0,0}; qa[nt]=(f32x2){0,0}; }

    for (int n = gw; n < NV; n += TW_A) {
        f32x16 x0, x1, g0, g1;
        voxel_core(in + ((long)n * P + col) * CIN, hi, wB, w1A, w2B,
                   hlw, wro, rdo0, rdo1, x0, x1, g0, g1);
        #pragma unroll
        for (int nt = 0; nt < 2; ++nt) {
            const f32x16& X = nt ? x1 : x0;
            const f32x16& G = nt ? g1 : g0;
            #pragma unroll
            for (int r = 0; r < 8; ++r) {
                f32x2 x2 = {X[2*r], X[2*r+1]};
                f32x2 g2 = {G[2*r], G[2*r+1]};
                f32x2 s2 = sigm2(g2);
                f32x2 xa2 = x2 * s2;
                sx[nt] += x2;  qx[nt] = __builtin_elementwise_fma(x2, x2, qx[nt]);
                sa[nt] += xa2; qa[nt] = __builtin_elementwise_fma(xa2, xa2, qa[nt]);
            }
        }
    }
    #pragma unroll
    for (int nt = 0; nt < 2; ++nt) {
        float vsx = sx[nt].x + sx[nt].y;  vsx += __shfl_xor(vsx, 32);
        float vqx = qx[nt].x + qx[nt].y;  vqx += __shfl_xor(vqx, 32);
        float vsa = sa[nt].x + sa[nt].y;  vsa += __shfl_xor(vsa, 32);
        float vqa = qa[nt].x + qa[nt].y;  vqa += __shfl_xor(vqa, 32);
        if (hi == 0) {
            red[wid][0][col][nt] = vsx; red[wid][1][col][nt] = vqx;
            red[wid][2][col][nt] = vsa; red[wid][3][col][nt] = vqa;
        }
    }
    __syncthreads();
    if (threadIdx.x < 256) {
        const int t = threadIdx.x, q = t >> 6, ch = t & 63, nt = ch >> 5, c = ch & 31;
        float s = 0.f;
        #pragma unroll
        for (int w = 0; w < WPB_A; ++w) s += red[w][q][c][nt];
        partials[blockIdx.x * 256 + t] = s;
    }
}

// ---- pass B: fp64 fixed-order reduce -> per-channel scale/bias ----
__global__ void pass_b(const float* __restrict__ partials,
                       const float* __restrict__ gamma,  const float* __restrict__ beta,
                       const float* __restrict__ gamma1, const float* __restrict__ beta1,
                       float* __restrict__ params)
{
    __shared__ double lds_s[4][COUT];
    const int t = threadIdx.x;
    double acc = 0.0;
    for (int b = 0; b < BLK_A; ++b) acc += (double)partials[b * 256 + t];
    lds_s[t >> 6][t & 63] = acc;
    __syncthreads();
    if (t < COUT) {
        const double M = (double)NV * P;
        double mx = lds_s[0][t] / M;
        double vx = lds_s[1][t] / M - mx * mx;
        double ma = lds_s[2][t] / M;
        double va = lds_s[3][t] / M - ma * ma;
        float sxp = (float)((double)gamma[t]  / sqrt(vx + (double)BN_EPS));
        float bxp = (float)((double)beta[t]   - mx * (double)sxp);
        float sap = (float)((double)gamma1[t] / sqrt(va + (double)BN_EPS));
        float bap = (float)((double)beta1[t]  - ma * (double)sap);
        params[t] = sxp; params[64 + t] = bxp; params[128 + t] = sap; params[192 + t] = bap;
    }
}

// ---- pass C: recompute, BN-affine+relu, mean_p / max_p, coalesced out ----
__global__ __launch_bounds__(THR_C, 4)
void pass_c(const float* __restrict__ in, const float* __restrict__ W,
            const float* __restrict__ W1, const float* __restrict__ W2,
            const float* __restrict__ params, float* __restrict__ out)
{
    __shared__ short hl[WPB_C][32 * HLS];
    const int lane = threadIdx.x & 63, wid = threadIdx.x >> 6;
    const int hi = lane >> 5, col = lane & 31;
    const int gw = blockIdx.x * WPB_C + wid;
    short* hlw = &hl[wid][0];
    int4 wro; int rdo0, rdo1;
    lds_offsets(col, hi, wro, rdo0, rdo1);

    short8 wB[2];
    wB[0] = load_k10(W + col * CIN, hi);
    wB[1] = load_k10(W + (32 + col) * CIN, hi);
    short8 w1A = load_k10(W1 + col * CIN, hi);
    short8 w2B[2][2];
    #pragma unroll
    for (int nt = 0; nt < 2; ++nt)
        #pragma unroll
        for (int kt = 0; kt < 2; ++kt)
            w2B[nt][kt] = load_k8(W2 + (nt * 32 + col) * CH + kt * 16 + hi * 8);

    f32x2 sxv[2], bxv[2], sav[2], bav[2];
    #pragma unroll
    for (int nt = 0; nt < 2; ++nt) {
        int ch = nt * 32 + col;
        sxv[nt] = (f32x2){params[ch],       params[ch]};
        bxv[nt] = (f32x2){params[64 + ch],  params[64 + ch]};
        sav[nt] = (f32x2){params[128 + ch], params[128 + ch]};
        bav[nt] = (f32x2){params[192 + ch], params[192 + ch]};
    }

    for (int n = gw; n < NV; n += TW_C) {
        f32x16 x0, x1, g0, g1;
        voxel_core(in + ((long)n * P + col) * CIN, hi, wB, w1A, w2B,
                   hlw, wro, rdo0, rdo1, x0, x1, g0, g1);
        f32x2 macc[2], xmax[2];
        #pragma unroll
        for (int nt = 0; nt < 2; ++nt) { macc[nt]=(f32x2){0,0}; xmax[nt]=(f32x2){0,0}; }
        #pragma unroll
        for (int nt = 0; nt < 2; ++nt) {
            const f32x16& X = nt ? x1 : x0;
            const f32x16& G = nt ? g1 : g0;
            #pragma unroll
            for (int r = 0; r < 8; ++r) {
                f32x2 x2 = {X[2*r], X[2*r+1]};
                f32x2 g2 = {G[2*r], G[2*r+1]};
                f32x2 s2 = sigm2(g2);
                f32x2 xa2 = x2 * s2;
                f32x2 zero = {0.f, 0.f};
                f32x2 ya2 = __builtin_elementwise_max(
                                __builtin_elementwise_fma(xa2, sav[nt], bav[nt]), zero);
                macc[nt] += ya2;
                f32x2 yx2 = __builtin_elementwise_max(
                                __builtin_elementwise_fma(x2, sxv[nt], bxv[nt]), zero);
                xmax[nt] = __builtin_elementwise_max(xmax[nt], yx2);
            }
        }
        float m0 = macc[0].x + macc[0].y;  m0 += __shfl_xor(m0, 32);
        float m1 = macc[1].x + macc[1].y;  m1 += __shfl_xor(m1, 32);
        float v0 = fmaxf(xmax[0].x, xmax[0].y); v0 = fmaxf(v0, __shfl_xor(v0, 32));
        float v1 = fmaxf(xmax[1].x, xmax[1].y); v1 = fmaxf(v1, __shfl_xor(v1, 32));
        float m  = hi ? m1 : m0;
        float v  = hi ? v1 : v0;
        out[(size_t)n * COUT + lane] = m * (1.f / (float)P) + v;   // lane == channel
    }
}

extern "C" void kernel_launch(void* const* d_in, const int* in_sizes, int n_in,
                              void* d_out, int out_size, void* d_ws, size_t ws_size,
                              hipStream_t stream)
{
    const float* in     = (const float*)d_in[0];
    const float* W      = (const float*)d_in[1];
    const float* W1     = (const float*)d_in[2];
    const float* W2     = (const float*)d_in[3];
    const float* gamma  = (const float*)d_in[4];
    const float* beta   = (const float*)d_in[5];
    const float* gamma1 = (const float*)d_in[6];
    const float* beta1  = (const float*)d_in[7];
    float* outp     = (float*)d_out;
    float* partials = (float*)d_ws;
    float* params   = partials + PART_FLOATS;

    pass_a<<<BLK_A, THR_A, 0, stream>>>(in, W, W1, W2, partials);
    pass_b<<<1, 256, 0, stream>>>(partials, gamma, beta, gamma1, beta1, params);
    pass_c<<<BLK_C, THR_C, 0, stream>>>(in, W, W1, W2, params, outp);
}